// Round 1
// baseline (185.069 us; speedup 1.0000x reference)
//
#include <hip/hip_runtime.h>
#include <math.h>

#define HH 256
#define WW 256
#define KC 32

// Kernel 1: build the DCT-II basis (unnormalized, matching torch_dct norm=None)
// in two layouts:
//   bHK[h*KC + k] = 2*cos(pi*(2h+1)*k/(2*256))   (stage-1: uniform-per-h reads)
//   bLW[l*WW + h] = same value                   (stage-2: contiguous-in-w reads)
__global__ void dct_basis_init(float* __restrict__ bHK, float* __restrict__ bLW) {
    const int h = threadIdx.x;  // 0..255
    for (int k = 0; k < KC; ++k) {
        double arg = M_PI * (2.0 * (double)h + 1.0) * (double)k / (2.0 * (double)HH);
        float v = (float)(2.0 * cos(arg));
        bHK[h * KC + k] = v;
        bLW[k * WW + h] = v;
    }
}

// Kernel 2: fused truncated 2D DCT. One block per (b,c) image.
//   Stage 1: T[k][w] = sum_h Ch[k][h] * x[h][w]   (thread owns column w = tid)
//   Stage 2: out[k][l] = sum_w T[k][w] * Cw[l][w] (thread owns 4 (k,l) pairs)
__global__ __launch_bounds__(256) void dct_trunc_kernel(
    const float* __restrict__ x,
    const float* __restrict__ bHK,
    const float* __restrict__ bLW,
    float* __restrict__ out) {
    // +4 pad: stage-2 ds_read_b128 of T[k][w..w+3] across 8 distinct k hits
    // bank-quads offset by 4 banks each -> conflict-free.
    __shared__ float T[KC][WW + 4];

    const int img = blockIdx.x;
    const int tid = threadIdx.x;
    const float* __restrict__ xi = x + (size_t)img * (HH * WW);

    // ---- Stage 1: per-column accumulation over all 256 rows ----
    float acc[KC];
    #pragma unroll
    for (int k = 0; k < KC; ++k) acc[k] = 0.0f;

    #pragma unroll 2
    for (int h = 0; h < HH; ++h) {
        float xv = xi[h * WW + tid];          // coalesced: 64 lanes x 4B contiguous
        const float* __restrict__ bh = bHK + h * KC;  // wave-uniform address
        #pragma unroll
        for (int k = 0; k < KC; ++k)
            acc[k] = fmaf(bh[k], xv, acc[k]); // basis load is uniform -> s_load
    }

    #pragma unroll
    for (int k = 0; k < KC; ++k) T[k][tid] = acc[k];
    __syncthreads();

    // ---- Stage 2: out[k][l] over 4 l's per thread ----
    const int k  = tid >> 3;          // 0..31
    const int l4 = (tid & 7) * 4;     // 0,4,...,28
    float4 a2 = make_float4(0.0f, 0.0f, 0.0f, 0.0f);

    const float* __restrict__ c0p = bLW + (l4 + 0) * WW;
    const float* __restrict__ c1p = bLW + (l4 + 1) * WW;
    const float* __restrict__ c2p = bLW + (l4 + 2) * WW;
    const float* __restrict__ c3p = bLW + (l4 + 3) * WW;

    #pragma unroll 4
    for (int w = 0; w < WW; w += 4) {
        float4 tv = *reinterpret_cast<const float4*>(&T[k][w]);
        float4 c0 = *reinterpret_cast<const float4*>(&c0p[w]);
        float4 c1 = *reinterpret_cast<const float4*>(&c1p[w]);
        float4 c2 = *reinterpret_cast<const float4*>(&c2p[w]);
        float4 c3 = *reinterpret_cast<const float4*>(&c3p[w]);
        a2.x = fmaf(tv.x, c0.x, fmaf(tv.y, c0.y, fmaf(tv.z, c0.z, fmaf(tv.w, c0.w, a2.x))));
        a2.y = fmaf(tv.x, c1.x, fmaf(tv.y, c1.y, fmaf(tv.z, c1.z, fmaf(tv.w, c1.w, a2.y))));
        a2.z = fmaf(tv.x, c2.x, fmaf(tv.y, c2.y, fmaf(tv.z, c2.z, fmaf(tv.w, c2.w, a2.z))));
        a2.w = fmaf(tv.x, c3.x, fmaf(tv.y, c3.y, fmaf(tv.z, c3.z, fmaf(tv.w, c3.w, a2.w))));
    }

    *reinterpret_cast<float4*>(&out[(size_t)img * (KC * KC) + k * KC + l4]) = a2;
}

extern "C" void kernel_launch(void* const* d_in, const int* in_sizes, int n_in,
                              void* d_out, int out_size, void* d_ws, size_t ws_size,
                              hipStream_t stream) {
    const float* x = (const float*)d_in[0];
    // d_in[1] is num_coeffs (==32); shapes are fixed, KC hard-coded.
    float* out = (float*)d_out;

    float* bHK = (float*)d_ws;              // 256*32 floats = 32 KiB
    float* bLW = bHK + HH * KC;             // 32*256 floats = 32 KiB

    dct_basis_init<<<1, 256, 0, stream>>>(bHK, bLW);

    const int n_imgs = in_sizes[0] / (HH * WW);   // 16*64 = 1024
    dct_trunc_kernel<<<n_imgs, 256, 0, stream>>>(x, bHK, bLW, out);
}